// Round 1
// baseline (372.593 us; speedup 1.0000x reference)
//
#include <hip/hip_runtime.h>

#define D 128
#define BN_EPS 1e-5f

// ---------------- degree count ----------------
__global__ void count_deg(const int* __restrict__ col, int* __restrict__ counts, int E) {
    int e = blockIdx.x * blockDim.x + threadIdx.x;
    if (e < E) atomicAdd(&counts[col[e]], 1);
}

// ---------------- dis = rsqrt(deg) ----------------
__global__ void compute_dis(const int* __restrict__ counts, float* __restrict__ dis, int n) {
    int i = blockIdx.x * blockDim.x + threadIdx.x;
    if (i < n) dis[i] = rsqrtf((float)counts[i] + 1.0f);
}

// ---------------- exclusive scan (single block, chunked) ----------------
__global__ __launch_bounds__(256) void scan_offsets(const int* __restrict__ counts,
                                                    int* __restrict__ offsets,
                                                    int* __restrict__ cursor, int n) {
    __shared__ int lds[256];
    int tid = threadIdx.x;
    int chunk = (n + 255) >> 8;
    int begin = tid * chunk;
    int end = begin + chunk;
    if (begin > n) begin = n;
    if (end > n) end = n;
    int s = 0;
    for (int i = begin; i < end; i++) s += counts[i];
    lds[tid] = s;
    __syncthreads();
    // Hillis-Steele inclusive scan
    for (int d = 1; d < 256; d <<= 1) {
        int t = (tid >= d) ? lds[tid - d] : 0;
        __syncthreads();
        lds[tid] += t;
        __syncthreads();
    }
    int run = lds[tid] - s;  // exclusive prefix of this thread's chunk
    for (int i = begin; i < end; i++) {
        offsets[i] = run;
        cursor[i] = run;
        run += counts[i];
    }
    if (tid == 255) offsets[n] = lds[255];
}

// ---------------- CSR fill (dest-sorted edge list) ----------------
__global__ void fill_csr(const int* __restrict__ row, const int* __restrict__ col,
                         int* __restrict__ cursor, int* __restrict__ esrc, int E) {
    int e = blockIdx.x * blockDim.x + threadIdx.x;
    if (e < E) {
        int c = col[e];
        int p = atomicAdd(&cursor[c], 1);
        esrc[p] = row[e];
    }
}

// ---------------- h = x @ W (fp32, tiled) ----------------
// block tile: 64 rows x 128 cols, K in chunks of 32. 256 threads:
// tx = tid&31 -> 4 cols each; ty = tid>>5 -> 8 rows each. acc[8][4].
__global__ __launch_bounds__(256) void gemm_xw(const float* __restrict__ x,
                                               const float* __restrict__ W,
                                               float* __restrict__ h, int n) {
    __shared__ float xs[32][68];   // [k][r], padded to 68 to spread banks, 16B-aligned rows
    __shared__ float ws[32][128];  // [k][c]
    int tid = threadIdx.x;
    int tx = tid & 31;
    int ty = tid >> 5;
    int row0 = blockIdx.x * 64;
    float acc[8][4] = {};

    for (int k0 = 0; k0 < 128; k0 += 32) {
        // stage x tile (64 rows x 32 k), transposed into xs[k][r]
        #pragma unroll
        for (int i = 0; i < 2; i++) {
            int li = tid + i * 256;     // 0..511 float4 units
            int r = li >> 3;            // 0..63
            int kq = li & 7;            // 0..7
            int grow = row0 + r;
            if (grow >= n) grow = n - 1;
            float4 v = *(const float4*)&x[(size_t)grow * D + k0 + kq * 4];
            xs[kq * 4 + 0][r] = v.x;
            xs[kq * 4 + 1][r] = v.y;
            xs[kq * 4 + 2][r] = v.z;
            xs[kq * 4 + 3][r] = v.w;
        }
        // stage W tile (32 k x 128 c)
        #pragma unroll
        for (int i = 0; i < 4; i++) {
            int li = tid + i * 256;     // 0..1023 float4 units
            int c4 = li & 31;
            int k = li >> 5;
            *(float4*)&ws[k][c4 * 4] = *(const float4*)&W[(size_t)(k0 + k) * D + c4 * 4];
        }
        __syncthreads();
        #pragma unroll
        for (int k = 0; k < 32; k++) {
            float4 wv = *(const float4*)&ws[k][tx * 4];
            float xr[8];
            *(float4*)&xr[0] = *(const float4*)&xs[k][ty * 8];
            *(float4*)&xr[4] = *(const float4*)&xs[k][ty * 8 + 4];
            #pragma unroll
            for (int r = 0; r < 8; r++) {
                acc[r][0] += xr[r] * wv.x;
                acc[r][1] += xr[r] * wv.y;
                acc[r][2] += xr[r] * wv.z;
                acc[r][3] += xr[r] * wv.w;
            }
        }
        __syncthreads();
    }
    #pragma unroll
    for (int r = 0; r < 8; r++) {
        int gr = row0 + ty * 8 + r;
        if (gr < n) *(float4*)&h[(size_t)gr * D + tx * 4] = *(float4*)&acc[r][0];
    }
}

// ---------------- aggregation: wave per node, gather via CSR ----------------
__global__ __launch_bounds__(256) void aggregate(const float* __restrict__ h,
                                                 const float* __restrict__ dis,
                                                 const int* __restrict__ offsets,
                                                 const int* __restrict__ esrc,
                                                 const float* __restrict__ bias,
                                                 float* __restrict__ out, int n) {
    int wave = threadIdx.x >> 6;
    int lane = threadIdx.x & 63;
    int node = blockIdx.x * 4 + wave;
    if (node >= n) return;
    float dc = dis[node];
    int s0 = offsets[node], s1 = offsets[node + 1];
    // self loop: dis[c]^2 * h[c]  (one dc here, one dc at the end)
    float2 hv = *(const float2*)&h[(size_t)node * D + lane * 2];
    float ax = dc * hv.x, ay = dc * hv.y;
    for (int e = s0; e < s1; e++) {
        int s = esrc[e];
        float dsv = dis[s];
        float2 hs = *(const float2*)&h[(size_t)s * D + lane * 2];
        ax += dsv * hs.x;
        ay += dsv * hs.y;
    }
    float2 bv = *(const float2*)&bias[lane * 2];
    float2 o;
    o.x = dc * ax + bv.x;
    o.y = dc * ay + bv.y;
    *(float2*)&out[(size_t)node * D + lane * 2] = o;
}

// ---------------- BN statistics ----------------
__global__ __launch_bounds__(256) void bn_stats(const float* __restrict__ out,
                                                float* __restrict__ gsum,
                                                float* __restrict__ gsumsq, int total) {
    int tid = threadIdx.x;
    float s1 = 0.f, s2 = 0.f;
    for (int i = blockIdx.x * 256 + tid; i < total; i += gridDim.x * 256) {
        float v = out[i];
        s1 += v;
        s2 += v * v;
    }
    __shared__ float l1[256], l2[256];
    l1[tid] = s1;
    l2[tid] = s2;
    __syncthreads();
    if (tid < 128) {
        atomicAdd(&gsum[tid], l1[tid] + l1[tid + 128]);
        atomicAdd(&gsumsq[tid], l2[tid] + l2[tid + 128]);
    }
}

// ---------------- BN finalize + ReLU (in place) ----------------
__global__ __launch_bounds__(256) void bn_finalize(float* __restrict__ out,
                                                   const float* __restrict__ gsum,
                                                   const float* __restrict__ gsumsq,
                                                   const float* __restrict__ gamma,
                                                   const float* __restrict__ beta,
                                                   int total, float invN) {
    int col = threadIdx.x & 127;
    float m = gsum[col] * invN;
    float var = gsumsq[col] * invN - m * m;
    float sc = rsqrtf(var + BN_EPS) * gamma[col];
    float sh = beta[col] - m * sc;
    for (int i = blockIdx.x * blockDim.x + threadIdx.x; i < total;
         i += gridDim.x * blockDim.x) {
        float v = out[i] * sc + sh;
        out[i] = v > 0.f ? v : 0.f;
    }
}

extern "C" void kernel_launch(void* const* d_in, const int* in_sizes, int n_in,
                              void* d_out, int out_size, void* d_ws, size_t ws_size,
                              hipStream_t stream) {
    const float* x     = (const float*)d_in[0];
    const int*   pos   = (const int*)d_in[1];
    const float* W     = (const float*)d_in[3];
    const float* bias  = (const float*)d_in[4];
    const float* gamma = (const float*)d_in[5];
    const float* beta  = (const float*)d_in[6];
    float* out = (float*)d_out;

    int N  = in_sizes[0] / D;
    int EP = in_sizes[1] / 2;
    const int* prow = pos;
    const int* pcol = pos + EP;

    auto align = [](size_t v) { return (v + 255) & ~(size_t)255; };
    char* p = (char*)d_ws;
    int*   counts = (int*)p;   p += align((size_t)N * 4);
    float* gsum   = (float*)p; p += align((size_t)D * 4);
    float* gsumsq = (float*)p; p += align((size_t)D * 4);
    size_t zbytes = (size_t)(p - (char*)d_ws);  // counts+gsum+gsumsq zeroed
    float* dis    = (float*)p; p += align((size_t)N * 4);
    int*   offs   = (int*)p;   p += align(((size_t)N + 1) * 4);
    int*   cursor = (int*)p;   p += align((size_t)N * 4);
    int*   esrc   = (int*)p;   p += align((size_t)EP * 4);
    float* h      = (float*)p; p += align((size_t)N * D * 4);

    hipMemsetAsync(d_ws, 0, zbytes, stream);
    count_deg<<<(EP + 255) / 256, 256, 0, stream>>>(pcol, counts, EP);
    compute_dis<<<(N + 255) / 256, 256, 0, stream>>>(counts, dis, N);
    scan_offsets<<<1, 256, 0, stream>>>(counts, offs, cursor, N);
    fill_csr<<<(EP + 255) / 256, 256, 0, stream>>>(prow, pcol, cursor, esrc, EP);
    gemm_xw<<<(N + 63) / 64, 256, 0, stream>>>(x, W, h, N);
    aggregate<<<(N + 3) / 4, 256, 0, stream>>>(h, dis, offs, esrc, bias, out, N);
    bn_stats<<<512, 256, 0, stream>>>(out, gsum, gsumsq, N * D);
    bn_finalize<<<1024, 256, 0, stream>>>(out, gsum, gsumsq, gamma, beta, N * D,
                                          1.0f / (float)N);
}

// Round 2
// 262.995 us; speedup vs baseline: 1.4167x; 1.4167x over previous
//
#include <hip/hip_runtime.h>

#define D 128
#define BN_EPS 1e-5f

// ---------------- degree count ----------------
__global__ void count_deg(const int* __restrict__ col, int* __restrict__ counts, int E) {
    int e = blockIdx.x * blockDim.x + threadIdx.x;
    if (e < E) atomicAdd(&counts[col[e]], 1);
}

// ---------------- dis = rsqrt(deg) ----------------
__global__ void compute_dis(const int* __restrict__ counts, float* __restrict__ dis, int n) {
    int i = blockIdx.x * blockDim.x + threadIdx.x;
    if (i < n) dis[i] = rsqrtf((float)counts[i] + 1.0f);
}

// ---------------- 3-phase device-wide exclusive scan ----------------
// phase 1: per-block (256 elems) reduce -> blocksums[b]
__global__ __launch_bounds__(256) void scan_p1(const int* __restrict__ counts,
                                               int* __restrict__ blocksums, int n) {
    __shared__ int lds[256];
    int tid = threadIdx.x;
    int i = blockIdx.x * 256 + tid;
    lds[tid] = (i < n) ? counts[i] : 0;
    __syncthreads();
    for (int d = 128; d > 0; d >>= 1) {
        if (tid < d) lds[tid] += lds[tid + d];
        __syncthreads();
    }
    if (tid == 0) blocksums[blockIdx.x] = lds[0];
}

// phase 2: single block scans blocksums (nb <= 256) -> exclusive blockoffs
__global__ __launch_bounds__(256) void scan_p2(const int* __restrict__ blocksums,
                                               int* __restrict__ blockoffs, int nb) {
    __shared__ int lds[256];
    int tid = threadIdx.x;
    int v = (tid < nb) ? blocksums[tid] : 0;
    lds[tid] = v;
    __syncthreads();
    for (int d = 1; d < 256; d <<= 1) {
        int t = (tid >= d) ? lds[tid - d] : 0;
        __syncthreads();
        lds[tid] += t;
        __syncthreads();
    }
    blockoffs[tid] = lds[tid] - v;  // exclusive
}

// phase 3: per-block local exclusive scan + block offset -> offsets, cursor
__global__ __launch_bounds__(256) void scan_p3(const int* __restrict__ counts,
                                               const int* __restrict__ blockoffs,
                                               int* __restrict__ offsets,
                                               int* __restrict__ cursor, int n) {
    __shared__ int lds[256];
    int tid = threadIdx.x;
    int i = blockIdx.x * 256 + tid;
    int v = (i < n) ? counts[i] : 0;
    lds[tid] = v;
    __syncthreads();
    for (int d = 1; d < 256; d <<= 1) {
        int t = (tid >= d) ? lds[tid - d] : 0;
        __syncthreads();
        lds[tid] += t;
        __syncthreads();
    }
    if (i <= n) {
        int off = blockoffs[blockIdx.x] + lds[tid] - v;  // exclusive prefix of i
        if (i < n) {
            offsets[i] = off;
            cursor[i] = off;
            if (i == n - 1) offsets[n] = off + v;
        }
    }
}

// ---------------- CSR fill (dest-sorted edge list) ----------------
__global__ void fill_csr(const int* __restrict__ row, const int* __restrict__ col,
                         int* __restrict__ cursor, int* __restrict__ esrc, int E) {
    int e = blockIdx.x * blockDim.x + threadIdx.x;
    if (e < E) {
        int c = col[e];
        int p = atomicAdd(&cursor[c], 1);
        esrc[p] = row[e];
    }
}

// ---------------- h = x @ W (fp32, tiled) ----------------
__global__ __launch_bounds__(256) void gemm_xw(const float* __restrict__ x,
                                               const float* __restrict__ W,
                                               float* __restrict__ h, int n) {
    __shared__ float xs[32][68];
    __shared__ float ws[32][128];
    int tid = threadIdx.x;
    int tx = tid & 31;
    int ty = tid >> 5;
    int row0 = blockIdx.x * 64;
    float acc[8][4] = {};

    for (int k0 = 0; k0 < 128; k0 += 32) {
        #pragma unroll
        for (int i = 0; i < 2; i++) {
            int li = tid + i * 256;
            int r = li >> 3;
            int kq = li & 7;
            int grow = row0 + r;
            if (grow >= n) grow = n - 1;
            float4 v = *(const float4*)&x[(size_t)grow * D + k0 + kq * 4];
            xs[kq * 4 + 0][r] = v.x;
            xs[kq * 4 + 1][r] = v.y;
            xs[kq * 4 + 2][r] = v.z;
            xs[kq * 4 + 3][r] = v.w;
        }
        #pragma unroll
        for (int i = 0; i < 4; i++) {
            int li = tid + i * 256;
            int c4 = li & 31;
            int k = li >> 5;
            *(float4*)&ws[k][c4 * 4] = *(const float4*)&W[(size_t)(k0 + k) * D + c4 * 4];
        }
        __syncthreads();
        #pragma unroll
        for (int k = 0; k < 32; k++) {
            float4 wv = *(const float4*)&ws[k][tx * 4];
            float xr[8];
            *(float4*)&xr[0] = *(const float4*)&xs[k][ty * 8];
            *(float4*)&xr[4] = *(const float4*)&xs[k][ty * 8 + 4];
            #pragma unroll
            for (int r = 0; r < 8; r++) {
                acc[r][0] += xr[r] * wv.x;
                acc[r][1] += xr[r] * wv.y;
                acc[r][2] += xr[r] * wv.z;
                acc[r][3] += xr[r] * wv.w;
            }
        }
        __syncthreads();
    }
    #pragma unroll
    for (int r = 0; r < 8; r++) {
        int gr = row0 + ty * 8 + r;
        if (gr < n) *(float4*)&h[(size_t)gr * D + tx * 4] = *(float4*)&acc[r][0];
    }
}

// ---------------- aggregation: wave per node, gather via CSR ----------------
__global__ __launch_bounds__(256) void aggregate(const float* __restrict__ h,
                                                 const float* __restrict__ dis,
                                                 const int* __restrict__ offsets,
                                                 const int* __restrict__ esrc,
                                                 const float* __restrict__ bias,
                                                 float* __restrict__ out, int n) {
    int wave = threadIdx.x >> 6;
    int lane = threadIdx.x & 63;
    int node = blockIdx.x * 4 + wave;
    if (node >= n) return;
    float dc = dis[node];
    int s0 = offsets[node], s1 = offsets[node + 1];
    float2 hv = *(const float2*)&h[(size_t)node * D + lane * 2];
    float ax = dc * hv.x, ay = dc * hv.y;
    for (int e = s0; e < s1; e++) {
        int s = esrc[e];
        float dsv = dis[s];
        float2 hs = *(const float2*)&h[(size_t)s * D + lane * 2];
        ax += dsv * hs.x;
        ay += dsv * hs.y;
    }
    float2 bv = *(const float2*)&bias[lane * 2];
    float2 o;
    o.x = dc * ax + bv.x;
    o.y = dc * ay + bv.y;
    *(float2*)&out[(size_t)node * D + lane * 2] = o;
}

// ---------------- BN statistics ----------------
__global__ __launch_bounds__(256) void bn_stats(const float* __restrict__ out,
                                                float* __restrict__ gsum,
                                                float* __restrict__ gsumsq, int total) {
    int tid = threadIdx.x;
    float s1 = 0.f, s2 = 0.f;
    for (int i = blockIdx.x * 256 + tid; i < total; i += gridDim.x * 256) {
        float v = out[i];
        s1 += v;
        s2 += v * v;
    }
    __shared__ float l1[256], l2[256];
    l1[tid] = s1;
    l2[tid] = s2;
    __syncthreads();
    if (tid < 128) {
        atomicAdd(&gsum[tid], l1[tid] + l1[tid + 128]);
        atomicAdd(&gsumsq[tid], l2[tid] + l2[tid + 128]);
    }
}

// ---------------- BN finalize + ReLU (in place) ----------------
__global__ __launch_bounds__(256) void bn_finalize(float* __restrict__ out,
                                                   const float* __restrict__ gsum,
                                                   const float* __restrict__ gsumsq,
                                                   const float* __restrict__ gamma,
                                                   const float* __restrict__ beta,
                                                   int total, float invN) {
    int col = threadIdx.x & 127;
    float m = gsum[col] * invN;
    float var = gsumsq[col] * invN - m * m;
    float sc = rsqrtf(var + BN_EPS) * gamma[col];
    float sh = beta[col] - m * sc;
    for (int i = blockIdx.x * blockDim.x + threadIdx.x; i < total;
         i += gridDim.x * blockDim.x) {
        float v = out[i] * sc + sh;
        out[i] = v > 0.f ? v : 0.f;
    }
}

extern "C" void kernel_launch(void* const* d_in, const int* in_sizes, int n_in,
                              void* d_out, int out_size, void* d_ws, size_t ws_size,
                              hipStream_t stream) {
    const float* x     = (const float*)d_in[0];
    const int*   pos   = (const int*)d_in[1];
    const float* W     = (const float*)d_in[3];
    const float* bias  = (const float*)d_in[4];
    const float* gamma = (const float*)d_in[5];
    const float* beta  = (const float*)d_in[6];
    float* out = (float*)d_out;

    int N  = in_sizes[0] / D;
    int EP = in_sizes[1] / 2;
    const int* prow = pos;
    const int* pcol = pos + EP;
    int nb = (N + 255) / 256;  // scan blocks (196 for N=50000, must be <= 256)

    auto align = [](size_t v) { return (v + 255) & ~(size_t)255; };
    char* p = (char*)d_ws;
    int*   counts    = (int*)p;   p += align((size_t)N * 4);
    float* gsum      = (float*)p; p += align((size_t)D * 4);
    float* gsumsq    = (float*)p; p += align((size_t)D * 4);
    size_t zbytes = (size_t)(p - (char*)d_ws);  // zeroed region
    float* dis       = (float*)p; p += align((size_t)N * 4);
    int*   offs      = (int*)p;   p += align(((size_t)N + 1) * 4);
    int*   cursor    = (int*)p;   p += align((size_t)N * 4);
    int*   blocksums = (int*)p;   p += align((size_t)256 * 4);
    int*   blockoffs = (int*)p;   p += align((size_t)256 * 4);
    int*   esrc      = (int*)p;   p += align((size_t)EP * 4);
    float* h         = (float*)p; p += align((size_t)N * D * 4);

    hipMemsetAsync(d_ws, 0, zbytes, stream);
    count_deg<<<(EP + 255) / 256, 256, 0, stream>>>(pcol, counts, EP);
    compute_dis<<<(N + 255) / 256, 256, 0, stream>>>(counts, dis, N);
    scan_p1<<<nb, 256, 0, stream>>>(counts, blocksums, N);
    scan_p2<<<1, 256, 0, stream>>>(blocksums, blockoffs, nb);
    scan_p3<<<nb, 256, 0, stream>>>(counts, blockoffs, offs, cursor, N);
    fill_csr<<<(EP + 255) / 256, 256, 0, stream>>>(prow, pcol, cursor, esrc, EP);
    gemm_xw<<<(N + 63) / 64, 256, 0, stream>>>(x, W, h, N);
    aggregate<<<(N + 3) / 4, 256, 0, stream>>>(h, dis, offs, esrc, bias, out, N);
    bn_stats<<<512, 256, 0, stream>>>(out, gsum, gsumsq, N * D);
    bn_finalize<<<1024, 256, 0, stream>>>(out, gsum, gsumsq, gamma, beta, N * D,
                                          1.0f / (float)N);
}

// Round 3
// 231.301 us; speedup vs baseline: 1.6109x; 1.1370x over previous
//
#include <hip/hip_runtime.h>

#define D 128
#define BN_EPS 1e-5f
#define NB_AGG 1024

__device__ __forceinline__ unsigned bf16rne(float f) {
    unsigned u = __float_as_uint(f);
    return (u + 0x7fffu + ((u >> 16) & 1u)) >> 16;
}
__device__ __forceinline__ float bflo(unsigned p) { return __uint_as_float(p << 16); }
__device__ __forceinline__ float bfhi(unsigned p) { return __uint_as_float(p & 0xffff0000u); }

// ---------------- degree count ----------------
__global__ void count_deg(const int* __restrict__ col, int* __restrict__ counts, int E) {
    int e = blockIdx.x * blockDim.x + threadIdx.x;
    if (e < E) atomicAdd(&counts[col[e]], 1);
}

// ---------------- dis + per-block sums (fused) ----------------
__global__ __launch_bounds__(256) void dis_scan_p1(const int* __restrict__ counts,
                                                   float* __restrict__ dis,
                                                   int* __restrict__ blocksums, int n) {
    __shared__ int lds[256];
    int tid = threadIdx.x;
    int i = blockIdx.x * 256 + tid;
    int c = (i < n) ? counts[i] : 0;
    if (i < n) dis[i] = rsqrtf((float)c + 1.0f);
    lds[tid] = c;
    __syncthreads();
    for (int d = 128; d > 0; d >>= 1) {
        if (tid < d) lds[tid] += lds[tid + d];
        __syncthreads();
    }
    if (tid == 0) blocksums[blockIdx.x] = lds[0];
}

// ---------------- scan of block sums (single block, nb <= 256) ----------------
__global__ __launch_bounds__(256) void scan_p2(const int* __restrict__ blocksums,
                                               int* __restrict__ blockoffs, int nb) {
    __shared__ int lds[256];
    int tid = threadIdx.x;
    int v = (tid < nb) ? blocksums[tid] : 0;
    lds[tid] = v;
    __syncthreads();
    for (int d = 1; d < 256; d <<= 1) {
        int t = (tid >= d) ? lds[tid - d] : 0;
        __syncthreads();
        lds[tid] += t;
        __syncthreads();
    }
    blockoffs[tid] = lds[tid] - v;
}

// ---------------- local scan + offsets ----------------
__global__ __launch_bounds__(256) void scan_p3(const int* __restrict__ counts,
                                               const int* __restrict__ blockoffs,
                                               int* __restrict__ offsets,
                                               int* __restrict__ cursor, int n) {
    __shared__ int lds[256];
    int tid = threadIdx.x;
    int i = blockIdx.x * 256 + tid;
    int v = (i < n) ? counts[i] : 0;
    lds[tid] = v;
    __syncthreads();
    for (int d = 1; d < 256; d <<= 1) {
        int t = (tid >= d) ? lds[tid - d] : 0;
        __syncthreads();
        lds[tid] += t;
        __syncthreads();
    }
    if (i < n) {
        int off = blockoffs[blockIdx.x] + lds[tid] - v;
        offsets[i] = off;
        cursor[i] = off;
        if (i == n - 1) offsets[n] = off + v;
    }
}

// ---------------- CSR fill: (src, dis[src]) pairs sorted by dest ----------------
__global__ void fill_csr(const int* __restrict__ row, const int* __restrict__ col,
                         const float* __restrict__ dis, int* __restrict__ cursor,
                         int2* __restrict__ epair, int E) {
    int e = blockIdx.x * blockDim.x + threadIdx.x;
    if (e < E) {
        int c = col[e];
        int r = row[e];
        int p = atomicAdd(&cursor[c], 1);
        epair[p] = make_int2(r, __float_as_int(dis[r]));
    }
}

// ---------------- h = x @ W (fp32 compute, bf16 store) ----------------
__global__ __launch_bounds__(256) void gemm_xw(const float* __restrict__ x,
                                               const float* __restrict__ W,
                                               unsigned* __restrict__ hb, int n) {
    __shared__ float xs[32][68];
    __shared__ float ws[32][128];
    int tid = threadIdx.x;
    int tx = tid & 31;
    int ty = tid >> 5;
    int row0 = blockIdx.x * 64;
    float acc[8][4] = {};

    for (int k0 = 0; k0 < 128; k0 += 32) {
        #pragma unroll
        for (int i = 0; i < 2; i++) {
            int li = tid + i * 256;
            int r = li >> 3;
            int kq = li & 7;
            int grow = row0 + r;
            if (grow >= n) grow = n - 1;
            float4 v = *(const float4*)&x[(size_t)grow * D + k0 + kq * 4];
            xs[kq * 4 + 0][r] = v.x;
            xs[kq * 4 + 1][r] = v.y;
            xs[kq * 4 + 2][r] = v.z;
            xs[kq * 4 + 3][r] = v.w;
        }
        #pragma unroll
        for (int i = 0; i < 4; i++) {
            int li = tid + i * 256;
            int c4 = li & 31;
            int k = li >> 5;
            *(float4*)&ws[k][c4 * 4] = *(const float4*)&W[(size_t)(k0 + k) * D + c4 * 4];
        }
        __syncthreads();
        #pragma unroll
        for (int k = 0; k < 32; k++) {
            float4 wv = *(const float4*)&ws[k][tx * 4];
            float xr[8];
            *(float4*)&xr[0] = *(const float4*)&xs[k][ty * 8];
            *(float4*)&xr[4] = *(const float4*)&xs[k][ty * 8 + 4];
            #pragma unroll
            for (int r = 0; r < 8; r++) {
                acc[r][0] += xr[r] * wv.x;
                acc[r][1] += xr[r] * wv.y;
                acc[r][2] += xr[r] * wv.z;
                acc[r][3] += xr[r] * wv.w;
            }
        }
        __syncthreads();
    }
    #pragma unroll
    for (int r = 0; r < 8; r++) {
        int gr = row0 + ty * 8 + r;
        if (gr < n) {
            uint2 pk;
            pk.x = bf16rne(acc[r][0]) | (bf16rne(acc[r][1]) << 16);
            pk.y = bf16rne(acc[r][2]) | (bf16rne(acc[r][3]) << 16);
            // ushort index = column; uint index = column pair
            *(uint2*)&hb[(size_t)gr * 64 + tx * 2] = pk;
        }
    }
}

// ---------------- aggregation (wave/node, bf16 gather, fused BN stats) ----------------
__global__ __launch_bounds__(256) void aggregate(const unsigned* __restrict__ hb,
                                                 const float* __restrict__ dis,
                                                 const int* __restrict__ offsets,
                                                 const int2* __restrict__ epair,
                                                 const float* __restrict__ bias,
                                                 float* __restrict__ out,
                                                 float* __restrict__ gsum,
                                                 float* __restrict__ gsumsq, int n) {
    int wave = threadIdx.x >> 6;
    int lane = threadIdx.x & 63;
    float2 bv = *(const float2*)&bias[lane * 2];
    float s1a = 0.f, s1b = 0.f, s2a = 0.f, s2b = 0.f;

    for (int node = blockIdx.x * 4 + wave; node < n; node += gridDim.x * 4) {
        float dc = dis[node];
        int s0 = offsets[node], s1 = offsets[node + 1];
        int cnt = s1 - s0;
        unsigned hp = hb[(size_t)node * 64 + lane];
        float ax = dc * bflo(hp), ay = dc * bfhi(hp);
        // lane-parallel preload of up to 64 (src, dis) pairs: one 8B load
        int2 ep = (lane < cnt) ? epair[s0 + lane] : make_int2(0, 0);
        int cap = cnt < 64 ? cnt : 64;
        int e = 0;
        for (; e + 4 <= cap; e += 4) {
            int sA = __shfl(ep.x, e), sB = __shfl(ep.x, e + 1);
            int sC = __shfl(ep.x, e + 2), sD = __shfl(ep.x, e + 3);
            float dA = __int_as_float(__shfl(ep.y, e));
            float dB = __int_as_float(__shfl(ep.y, e + 1));
            float dC = __int_as_float(__shfl(ep.y, e + 2));
            float dD = __int_as_float(__shfl(ep.y, e + 3));
            unsigned hA = hb[(size_t)sA * 64 + lane];
            unsigned hB = hb[(size_t)sB * 64 + lane];
            unsigned hC = hb[(size_t)sC * 64 + lane];
            unsigned hD = hb[(size_t)sD * 64 + lane];
            ax += dA * bflo(hA); ay += dA * bfhi(hA);
            ax += dB * bflo(hB); ay += dB * bfhi(hB);
            ax += dC * bflo(hC); ay += dC * bfhi(hC);
            ax += dD * bflo(hD); ay += dD * bfhi(hD);
        }
        for (; e < cap; e++) {
            int s = __shfl(ep.x, e);
            float dv = __int_as_float(__shfl(ep.y, e));
            unsigned hq = hb[(size_t)s * 64 + lane];
            ax += dv * bflo(hq); ay += dv * bfhi(hq);
        }
        for (e = 64; e < cnt; e++) {  // rare deg>64 tail
            int2 q = epair[s0 + e];
            float dv = __int_as_float(q.y);
            unsigned hq = hb[(size_t)q.x * 64 + lane];
            ax += dv * bflo(hq); ay += dv * bfhi(hq);
        }
        float ox = dc * ax + bv.x;
        float oy = dc * ay + bv.y;
        *(float2*)&out[(size_t)node * D + lane * 2] = make_float2(ox, oy);
        s1a += ox; s1b += oy;
        s2a += ox * ox; s2b += oy * oy;
    }

    // reduce BN partials across the 4 waves, then 256 global atomics per block
    __shared__ float l1[4][128], l2[4][128];
    l1[wave][lane * 2] = s1a; l1[wave][lane * 2 + 1] = s1b;
    l2[wave][lane * 2] = s2a; l2[wave][lane * 2 + 1] = s2b;
    __syncthreads();
    int tid = threadIdx.x;
    if (tid < 128) {
        float a = l1[0][tid] + l1[1][tid] + l1[2][tid] + l1[3][tid];
        float b = l2[0][tid] + l2[1][tid] + l2[2][tid] + l2[3][tid];
        atomicAdd(&gsum[tid], a);
        atomicAdd(&gsumsq[tid], b);
    }
}

// ---------------- BN finalize + ReLU (in place) ----------------
__global__ __launch_bounds__(256) void bn_finalize(float* __restrict__ out,
                                                   const float* __restrict__ gsum,
                                                   const float* __restrict__ gsumsq,
                                                   const float* __restrict__ gamma,
                                                   const float* __restrict__ beta,
                                                   int total, float invN) {
    int col = threadIdx.x & 127;
    float m = gsum[col] * invN;
    float var = gsumsq[col] * invN - m * m;
    float sc = rsqrtf(var + BN_EPS) * gamma[col];
    float sh = beta[col] - m * sc;
    for (int i = blockIdx.x * blockDim.x + threadIdx.x; i < total;
         i += gridDim.x * blockDim.x) {
        float v = out[i] * sc + sh;
        out[i] = v > 0.f ? v : 0.f;
    }
}

extern "C" void kernel_launch(void* const* d_in, const int* in_sizes, int n_in,
                              void* d_out, int out_size, void* d_ws, size_t ws_size,
                              hipStream_t stream) {
    const float* x     = (const float*)d_in[0];
    const int*   pos   = (const int*)d_in[1];
    const float* W     = (const float*)d_in[3];
    const float* bias  = (const float*)d_in[4];
    const float* gamma = (const float*)d_in[5];
    const float* beta  = (const float*)d_in[6];
    float* out = (float*)d_out;

    int N  = in_sizes[0] / D;
    int EP = in_sizes[1] / 2;
    const int* prow = pos;
    const int* pcol = pos + EP;
    int nb = (N + 255) / 256;

    auto align = [](size_t v) { return (v + 255) & ~(size_t)255; };
    char* p = (char*)d_ws;
    int*      counts    = (int*)p;      p += align((size_t)N * 4);
    float*    gsum      = (float*)p;    p += align((size_t)D * 4);
    float*    gsumsq    = (float*)p;    p += align((size_t)D * 4);
    size_t zbytes = (size_t)(p - (char*)d_ws);
    float*    dis       = (float*)p;    p += align((size_t)N * 4);
    int*      offs      = (int*)p;      p += align(((size_t)N + 1) * 4);
    int*      cursor    = (int*)p;      p += align((size_t)N * 4);
    int*      blocksums = (int*)p;      p += align((size_t)256 * 4);
    int*      blockoffs = (int*)p;      p += align((size_t)256 * 4);
    int2*     epair     = (int2*)p;     p += align((size_t)EP * 8);
    unsigned* hb        = (unsigned*)p; p += align((size_t)N * 64 * 4);

    hipMemsetAsync(d_ws, 0, zbytes, stream);
    count_deg<<<(EP + 255) / 256, 256, 0, stream>>>(pcol, counts, EP);
    dis_scan_p1<<<nb, 256, 0, stream>>>(counts, dis, blocksums, N);
    scan_p2<<<1, 256, 0, stream>>>(blocksums, blockoffs, nb);
    scan_p3<<<nb, 256, 0, stream>>>(counts, blockoffs, offs, cursor, N);
    fill_csr<<<(EP + 255) / 256, 256, 0, stream>>>(prow, pcol, dis, cursor, epair, EP);
    gemm_xw<<<(N + 63) / 64, 256, 0, stream>>>(x, W, hb, N);
    aggregate<<<NB_AGG, 256, 0, stream>>>(hb, dis, offs, epair, bias, out, gsum, gsumsq, N);
    bn_finalize<<<1024, 256, 0, stream>>>(out, gsum, gsumsq, gamma, beta, N * D,
                                          1.0f / (float)N);
}